// Round 6
// baseline (326.250 us; speedup 1.0000x reference)
//
#include <hip/hip_runtime.h>
#include <hip/hip_fp16.h>

#define M_DIM 16384
#define K_DIM 2048
#define N_DIM 2048

#define BM 256
#define BN 256
#define BK 64
#define NT (K_DIM / BK)

typedef int int4v  __attribute__((ext_vector_type(4)));
typedef int int16v __attribute__((ext_vector_type(16)));

__device__ __forceinline__ void gl_lds16(const void* g, void* l) {
    __builtin_amdgcn_global_load_lds(
        (const __attribute__((address_space(1))) void*)g,
        (__attribute__((address_space(3))) void*)l,
        16, 0, 0);
}

__device__ __forceinline__ int pack4(int4v v) {
    return (v[0] & 255) | ((v[1] & 255) << 8) | ((v[2] & 255) << 16) | (v[3] << 24);
}

// x: int32 [M,K] -> int8 [M,K]; lane-contiguous loads/stores
__global__ void pack_x_kernel(const int* __restrict__ x, char* __restrict__ xp) {
    const int4v* src = (const int4v*)x;
    int* dst = (int*)xp;
    int base = blockIdx.x * 1024 + threadIdx.x;
#pragma unroll
    for (int j = 0; j < 4; ++j) {
        int i = base + j * 256;
        dst[i] = pack4(src[i]);
    }
}

// weight: int32 [K,N] -> int8 WT [N,K] (transpose + pack), 64x64 tiles via LDS
__global__ void wt_pack_kernel(const int* __restrict__ w, char* __restrict__ wt) {
    __shared__ char tile[64][68];
    int b  = blockIdx.x;
    int k0 = (b & 31) * 64;
    int n0 = (b >> 5) * 64;
    int t  = threadIdx.x;
    int r  = t >> 2;
    int c  = (t & 3) * 16;

    const int* src = w + (size_t)(k0 + r) * N_DIM + n0 + c;
    int4v a = *(const int4v*)(src + 0);
    int4v bb = *(const int4v*)(src + 4);
    int4v cc = *(const int4v*)(src + 8);
    int4v dd = *(const int4v*)(src + 12);
    *(int*)&tile[r][c + 0]  = pack4(a);
    *(int*)&tile[r][c + 4]  = pack4(bb);
    *(int*)&tile[r][c + 8]  = pack4(cc);
    *(int*)&tile[r][c + 12] = pack4(dd);
    __syncthreads();

    char buf[16];
#pragma unroll
    for (int j = 0; j < 16; ++j) buf[j] = tile[c + j][r];
    *(int4v*)(wt + (size_t)(n0 + r) * K_DIM + k0 + c) = *(int4v*)buf;
}

// GEMM: A int8 [M,K], BT int8 [N,K] -> C fp32 [M,N] (+bias)
// 256x256 tile, BK=64, 512 thr = 8 waves (2M x 4N), wave tile 128x64 =
// acc[4][2] (128 acc regs). TRIPLE-buffered LDS (3 x 32 KiB = 96 KiB,
// 1 block/CU), prefetch distance 2, COUNTED vmcnt -- never drained to 0 in
// the main loop (m218: counted-vs-drain0 = +38-73%; m233: the drain+barrier
// rendezvous, not dataflow, dominates 2-phase loops). Steady state per tile:
//   STAGE(tile t+2 -> buf (t+2)%3)   [4 gl_lds/thread]
//   compute tile t on buf t%3        [12 ds_read_b128 + 16 MFMA / wave]
//   s_waitcnt vmcnt(4)               [drains tile t+1's loads; t+2 stays
//                                     in flight ACROSS the barrier]
//   s_barrier
// Each prefetch gets ~2 tile-periods of slack -> L2/HBM latency jitter never
// reaches the rendezvous. Tail: prefetch index clamped to NT-1 (duplicate
// re-stage of the last tile, byte-identical data -> benign) so the vmcnt(4)
// ledger stays exact through the epilogue.
// LDS layout (16B slots, 4 chunks/row): slot = r*4 + (cg ^ ((r>>1)&3)).
// The (r>>1) XOR makes slot%8 distinct across each 8-lane read group (all 32
// banks covered); plain ^(r&3) would 2-way collide (lanes l and l+4).
// Staging slot-linear (gl_lds wave-uniform dest) with pre-swizzled global src.
__global__ __launch_bounds__(512, 2)
void gemm_i8_kernel(const char* __restrict__ A, const char* __restrict__ BT,
                    const __half* __restrict__ bias, float* __restrict__ C) {
    __shared__ char Asm[3][BM * BK];   // 3 x 16384 B
    __shared__ char Bsm[3][BN * BK];   // 3 x 16384 B

    const int bid = blockIdx.x;
    const int mt = bid & 63;            // m fastest: B panel (512 KB) stays hot in L2
    const int nt = bid >> 6;
    const int R0 = mt * BM, C0 = nt * BN;

    const int t = threadIdx.x;
    const int lane = t & 63;
    const int w = t >> 6;
    const int wm = w >> 2;              // 0..1 row-half (128 rows)
    const int wn = w & 3;               // 0..3 col-quarter (64 cols)
    const int l31 = lane & 31, khl = lane >> 5;

    int16v acc[4][2];
#pragma unroll
    for (int i = 0; i < 4; ++i)
#pragma unroll
        for (int j = 0; j < 2; ++j) acc[i][j] = (int16v)0;

    // staging: thread owns slots t + 512*j (j=0..1); slot s -> row s>>2,
    // stored chunk s&3, global chunk cg = (s&3) ^ ((row>>1)&3)
    unsigned aoff[2], boff[2];
    int ldst[2];
#pragma unroll
    for (int j = 0; j < 2; ++j) {
        int s = t + j * 512;
        int r = s >> 2;
        int cg = (s & 3) ^ ((r >> 1) & 3);
        aoff[j] = (unsigned)(R0 + r) * K_DIM + cg * 16;
        boff[j] = (unsigned)(C0 + r) * K_DIM + cg * 16;
        ldst[j] = s * 16;
    }

    // fragment row-slot bases (row*4); (row>>1)&3 == (l31>>1)&3 (bases mult. 32)
    int arow4[4], brow4[2];
#pragma unroll
    for (int i = 0; i < 4; ++i) arow4[i] = (wm * 128 + i * 32 + l31) * 4;
#pragma unroll
    for (int j = 0; j < 2; ++j) brow4[j] = (wn * 64 + j * 32 + l31) * 4;
    const int x3 = (l31 >> 1) & 3;
    const int ch0 = khl ^ x3;            // ks=0: logical chunk khl
    const int ch1 = (2 + khl) ^ x3;      // ks=1: logical chunk 2+khl

#define STAGE(buf, kt)                                                          \
    {                                                                           \
        const unsigned kb = (unsigned)(kt) * BK;                                \
        gl_lds16(A + aoff[0] + kb, &Asm[buf][ldst[0]]);                         \
        gl_lds16(A + aoff[1] + kb, &Asm[buf][ldst[1]]);                         \
        gl_lds16(BT + boff[0] + kb, &Bsm[buf][ldst[0]]);                        \
        gl_lds16(BT + boff[1] + kb, &Bsm[buf][ldst[1]]);                        \
    }

    // prologue: stage tiles 0,1; wait only for tile 0 (tile 1 stays in flight)
    STAGE(0, 0)
    STAGE(1, 1)
    asm volatile("s_waitcnt vmcnt(4)" ::: "memory");
    __builtin_amdgcn_s_barrier();

    int bc = 0, bp = 2;
    for (int kt = 0; kt < NT; ++kt) {
        const int tpf = (kt + 2 < NT) ? kt + 2 : NT - 1;   // clamp keeps ledger exact
        STAGE(bp, tpf)
#pragma unroll
        for (int ks = 0; ks < 2; ++ks) {
            const int ch = ks ? ch1 : ch0;
            int4v af[4], bf[2];
#pragma unroll
            for (int i = 0; i < 4; ++i)
                af[i] = *(const int4v*)&Asm[bc][(arow4[i] + ch) * 16];
#pragma unroll
            for (int j = 0; j < 2; ++j)
                bf[j] = *(const int4v*)&Bsm[bc][(brow4[j] + ch) * 16];
#pragma unroll
            for (int i = 0; i < 4; ++i) {
#pragma unroll
                for (int j = 0; j < 2; ++j)
                    acc[i][j] = __builtin_amdgcn_mfma_i32_32x32x32_i8(
                        af[i], bf[j], acc[i][j], 0, 0, 0);
            }
        }
        asm volatile("s_waitcnt vmcnt(4)" ::: "memory");   // next tile ready; newest 4 stay in flight
        __builtin_amdgcn_s_barrier();
        bc = (bc == 2) ? 0 : bc + 1;
        bp = (bp == 2) ? 0 : bp + 1;
    }
#undef STAGE

    // epilogue: C/D layout col=lane&31, row=(reg&3)+8*(reg>>2)+4*(lane>>5)
    const int col = l31;
    const int rb = khl * 4;
#pragma unroll
    for (int j = 0; j < 2; ++j) {
        const int cn = C0 + wn * 64 + j * 32 + col;
        const float bv = __half2float(bias[cn]);
#pragma unroll
        for (int i = 0; i < 4; ++i) {
            const int rm = R0 + wm * 128 + i * 32 + rb;
#pragma unroll
            for (int reg = 0; reg < 16; ++reg) {
                const int row = rm + (reg & 3) + 8 * (reg >> 2);
                C[(size_t)row * N_DIM + cn] = (float)acc[i][j][reg] + bv;
            }
        }
    }
}

extern "C" void kernel_launch(void* const* d_in, const int* in_sizes, int n_in,
                              void* d_out, int out_size, void* d_ws, size_t ws_size,
                              hipStream_t stream) {
    const int* x = (const int*)d_in[0];
    const int* wgt = (const int*)d_in[1];
    const __half* bias = (const __half*)d_in[2];
    float* out = (float*)d_out;

    char* xp = (char*)d_ws;                                   // 32 MiB packed A
    char* wt = (char*)d_ws + (size_t)M_DIM * K_DIM;           // 4 MiB packed W^T

    pack_x_kernel<<<(M_DIM * (size_t)K_DIM) / 4 / 1024, 256, 0, stream>>>(x, xp);
    wt_pack_kernel<<<(K_DIM / 64) * (N_DIM / 64), 256, 0, stream>>>(wgt, wt);
    gemm_i8_kernel<<<(M_DIM / BM) * (N_DIM / BN), 512, 0, stream>>>(xp, wt, bias, out);
}